// Round 9
// baseline (52.342 us; speedup 1.0000x reference)
//
#include <hip/hip_runtime.h>
#include <math.h>

#define B 8
#define G 64
#define S 256
#define DIM 41
#define ET 128
#define H 8
#define EK 16
#define NH 127
#define HD (H*DIM)   // 328
#define EROW 257     // padded e-row
#define NBC 129      // C rows: 128 query dims + 1 bias row

// ---------------- K1 "prep": embitsT + C-build + keyT ----------------
// grid 649 x 256:
//   [0,512): embitsT per (b,g) (verbatim proven r3/r7 code)
//   [512,641): C[i][h*41+d] = sum_j Wq'[i][h16+j] * Wk[d][h16+j]  (Wq' row 128 = bq)
//              cb[i][h]     = sum_j Wq'[i][h16+j] * bk[h16+j]
//   [641,649): keyT[b][d][s] = key[b][s][d]
__global__ __launch_bounds__(256) void prep_kernel(const float* __restrict__ key,
                                                   const float* __restrict__ mask,
                                                   const float* __restrict__ qt,
                                                   const float* __restrict__ tt,
                                                   const float* __restrict__ stride_in,
                                                   const float* __restrict__ Wq,
                                                   const float* __restrict__ bq,
                                                   const float* __restrict__ Wk,
                                                   const float* __restrict__ bk,
                                                   const float* __restrict__ Wr,
                                                   const float* __restrict__ br,
                                                   unsigned int* __restrict__ embitsT,
                                                   float* __restrict__ C,
                                                   float* __restrict__ cb,
                                                   float* __restrict__ keyT) {
    __shared__ float smem[5248 + 64];
    const int bid = blockIdx.x;
    const int tid = threadIdx.x;

    if (bid < 512) {
        // ---- embitsT per (b,g): bit(s,d) = window & mask, d-major words:
        // embitsT[bg*328 + d*8 + (s>>5)], bit (s&31)
        float* mlds = smem;
        float* strd = smem + 5248;
        const int bg = bid;
        const int b = bg >> 6, g = bg & 63;
        if (tid < DIM) {
            float a = br[tid];
            for (int i = 0; i < DIM; ++i) a = fmaf(stride_in[i], Wr[i * DIM + tid], a);
            strd[tid] = 1.0f / (1.0f + expf(-a));
        }
        __syncthreads();
        const float qtg = qt[g];
        for (int rr = 0; rr < 2; ++rr) {
            for (int idx = tid; idx < 5248; idx += 256)
                mlds[idx] = mask[(size_t)b * S * DIM + rr * 5248 + idx];
            __syncthreads();
            if (tid < 128) {
                const int s = rr * 128 + tid;
                const float t = tt[b * S + s];
                const int wv = tid >> 6;
                const int w = rr * 2 + wv;
                unsigned int* op = embitsT + (size_t)bg * (DIM * 8) + w * 2;
#pragma unroll
                for (int d = 0; d < DIM; ++d) {
                    const float sd = strd[d];
                    const int ok = (t >= qtg - sd) & (t <= qtg + sd) & (mlds[tid * DIM + d] != 0.0f);
                    const unsigned long long bal = __ballot(ok);
                    if ((tid & 63) == 0) {
                        op[d * 8 + 0] = (unsigned int)bal;
                        op[d * 8 + 1] = (unsigned int)(bal >> 32);
                    }
                }
            }
            __syncthreads();
        }
    } else if (bid < 641) {
        // ---- C-build: one block per i (0..128)
        const int i = bid - 512;
        if (tid < ET) smem[tid] = (i < 128) ? Wq[(size_t)i * ET + tid] : bq[tid];
        __syncthreads();
        for (int o = tid; o < 336; o += 256) {
            if (o < 328) {
                const int h = o / DIM, d = o - h * DIM;
                float a = 0.f;
#pragma unroll
                for (int j = 0; j < 16; ++j)
                    a = fmaf(smem[h * 16 + j], Wk[(size_t)d * ET + h * 16 + j], a);
                C[(size_t)i * 328 + o] = a;
            } else {
                const int h = o - 328;
                float a = 0.f;
#pragma unroll
                for (int j = 0; j < 16; ++j)
                    a = fmaf(smem[h * 16 + j], bk[h * 16 + j], a);
                cb[i * 8 + h] = a;
            }
        }
    } else {
        // ---- keyT[b][d][s] = key[b][s][d]; writes coalesced
        const int b = bid - 641;
        for (int idx = tid; idx < DIM * S; idx += 256) {
            const int d = idx >> 8, s = idx & 255;
            keyT[(size_t)b * (DIM * S) + idx] = key[(size_t)b * S * DIM + s * DIM + d];
        }
    }
}

// ---------------- K2 "main": qk + scores + softmax + weighted + outproj, per (b,g) ----------------
// 512 threads (8 waves), ~14 KB LDS.
__global__ __launch_bounds__(512) void main_kernel(const float* __restrict__ query,
                                                   const float* __restrict__ C,
                                                   const float* __restrict__ cb,
                                                   const float* __restrict__ keyT,
                                                   const unsigned int* __restrict__ embitsT,
                                                   const float* __restrict__ value,
                                                   const float* __restrict__ Wo,
                                                   const float* __restrict__ bo,
                                                   float* __restrict__ out) {
    __shared__ float qrow[NBC];        // query row + 1.0 bias slot
    __shared__ float qkl[H * 44];      // per-head transformed q (DIM-dim, padded row)
    __shared__ float sbl[H];           // per-head scalar bias term
    __shared__ float se[H * EROW];     // scores then e
    __shared__ float Mb[H];
    __shared__ float xrow[HD];
    __shared__ float po[4][128];

    const int bg = blockIdx.x;
    const int b = bg >> 6;
    const int tid = threadIdx.x;

    if (tid < ET) qrow[tid] = query[(size_t)bg * ET + tid];
    if (tid == ET) qrow[ET] = 1.0f;
    __syncthreads();

    // qk phase: threads 0..327 -> (h,d); 328..335 -> sb[h]
    if (tid < HD) {
        float a = 0.f;
        for (int i = 0; i < NBC; ++i)
            a = fmaf(qrow[i], C[(size_t)i * 328 + tid], a);
        const int h = tid / DIM, d = tid - h * DIM;
        qkl[h * 44 + d] = a;
    } else if (tid < HD + H) {
        const int h = tid - HD;
        float a = 0.f;
        for (int i = 0; i < NBC; ++i)
            a = fmaf(qrow[i], cb[i * 8 + h], a);
        sbl[h] = a;
    }
    __syncthreads();

    // scores: thread = s (256 threads), 8 heads in registers, keyT lane-coalesced
    float sc8[H];
    if (tid < S) {
        float acc[H];
#pragma unroll
        for (int h = 0; h < H; ++h) acc[h] = 0.f;
        const float* kT = keyT + (size_t)b * (DIM * S) + tid;
        for (int d = 0; d < DIM; ++d) {
            const float kd = kT[(size_t)d * S];
#pragma unroll
            for (int h = 0; h < H; ++h)
                acc[h] = fmaf(kd, qkl[h * 44 + d], acc[h]);
        }
#pragma unroll
        for (int h = 0; h < H; ++h) {
            sc8[h] = (acc[h] + sbl[h]) * 0.25f;   // 1/sqrt(EK)
            se[h * EROW + tid] = sc8[h];
        }
    }
    __syncthreads();

    // per-head max: threads 0..255, h = tid>>5, j = tid&31 (proven)
    if (tid < S) {
        const int h = tid >> 5, j = tid & 31;
        float m = se[h * EROW + j];
#pragma unroll
        for (int k = 1; k < 8; ++k) m = fmaxf(m, se[h * EROW + j + 32 * k]);
#pragma unroll
        for (int off = 16; off; off >>= 1) m = fmaxf(m, __shfl_xor(m, off, 32));
        if (j == 0) Mb[h] = m;
    }
    __syncthreads();

    // exp (from registers)
    if (tid < S) {
#pragma unroll
        for (int h = 0; h < H; ++h) se[h * EROW + tid] = __expf(sc8[h] - Mb[h]);
    }
    __syncthreads();

    // weighted phase (proven r8): wave = head, lane = d; reduction-free
    {
        const int w = tid >> 6;         // head 0..7
        const int d = tid & 63;
        if (d < DIM) {
            const uint4* bp = reinterpret_cast<const uint4*>(embitsT + (size_t)bg * (DIM * 8) + d * 8);
            const uint4 b0 = bp[0], b1 = bp[1];
            const unsigned int bw[8] = {b0.x, b0.y, b0.z, b0.w, b1.x, b1.y, b1.z, b1.w};
            const float* er = &se[w * EROW];
            const float* vb = value + (size_t)b * S * DIM + d;
            float Ssum = 0.f, acc = 0.f;
#pragma unroll
            for (int k = 0; k < 8; ++k) {
                const unsigned int wv = bw[k];
#pragma unroll 8
                for (int i = 0; i < 32; ++i) {
                    const int s = k * 32 + i;
                    const float e = er[s];
                    const float v = vb[(size_t)s * DIM];
                    const float wgt = ((wv >> i) & 1u) ? e : 0.f;
                    Ssum += wgt;
                    acc = fmaf(wgt, v, acc);
                }
            }
            float r;
            if (Ssum != 0.f) {
                r = acc / Ssum;
            } else {
                // all-masked column: uniform softmax -> column mean (never taken in practice)
                float vs = 0.f;
                for (int s2 = 0; s2 < S; ++s2) vs += vb[(size_t)s2 * DIM];
                r = vs * (1.0f / S);
            }
            xrow[w * DIM + d] = r;
        }
    }
    __syncthreads();

    // out-proj (proven r4): 4 i-chunks of 82, lanes n = tid&127
    {
        const int n = tid & 127, c = tid >> 7;
        if (n < NH) {
            const int i0 = c * 82;
            float a0 = 0.f, a1 = 0.f;
#pragma unroll 2
            for (int i = i0; i < i0 + 82; i += 2) {
                a0 = fmaf(xrow[i],     Wo[(size_t)i * NH + n],       a0);
                a1 = fmaf(xrow[i + 1], Wo[(size_t)(i + 1) * NH + n], a1);
            }
            po[c][n] = a0 + a1;
        }
    }
    __syncthreads();
    if (tid < NH)
        out[(size_t)bg * NH + tid] = bo[tid] + ((po[0][tid] + po[1][tid]) + (po[2][tid] + po[3][tid]));
}

extern "C" void kernel_launch(void* const* d_in, const int* in_sizes, int n_in,
                              void* d_out, int out_size, void* d_ws, size_t ws_size,
                              hipStream_t stream) {
    const float* query     = (const float*)d_in[0];
    const float* key       = (const float*)d_in[1];
    const float* value     = (const float*)d_in[2];
    const float* mask      = (const float*)d_in[3];
    const float* qt        = (const float*)d_in[4];
    const float* tt        = (const float*)d_in[5];
    const float* stride_in = (const float*)d_in[6];
    const float* Wq        = (const float*)d_in[7];
    const float* bq        = (const float*)d_in[8];
    const float* Wk        = (const float*)d_in[9];
    const float* bk        = (const float*)d_in[10];
    const float* Wo        = (const float*)d_in[11];
    const float* bo        = (const float*)d_in[12];
    const float* Wr        = (const float*)d_in[13];
    const float* br        = (const float*)d_in[14];
    float* out = (float*)d_out;

    // workspace layout
    unsigned int* embitsT = (unsigned int*)d_ws;          // B*G*DIM*8 = 167936 u32
    float* C    = (float*)(embitsT + (size_t)B * G * DIM * 8);  // 129*328 f32
    float* cb   = C + (size_t)NBC * 328;                  // 129*8 f32
    float* keyT = cb + (size_t)NBC * 8;                   // B*DIM*S f32

    prep_kernel<<<649, 256, 0, stream>>>(key, mask, qt, tt, stride_in, Wq, bq,
                                         Wk, bk, Wr, br, embitsT, C, cb, keyT);
    main_kernel<<<B * G, 512, 0, stream>>>(query, C, cb, keyT, embitsT, value, Wo, bo, out);
}

// Round 10
// 43.856 us; speedup vs baseline: 1.1935x; 1.1935x over previous
//
#include <hip/hip_runtime.h>
#include <math.h>

#define B 8
#define G 64
#define S 256
#define DIM 41
#define ET 128
#define H 8
#define EK 16
#define NH 127
#define HD (H*DIM)   // 328
#define EROW 257     // padded e-row in attn LDS

// ---------------- K1 "prep": kproj->kpT4, qproj, embitsT (verbatim proven r3) ----------------
// grid 1792 x 256:
//   [0,1024): kproj, 2 rows each; [1024,1280): qproj, 2 rows each;
//   [1280,1792): embitsT per (b,g) (mask staged via LDS, coalesced)
__global__ __launch_bounds__(256) void prep_kernel(const float* __restrict__ key,
                                                   const float* __restrict__ Wk,
                                                   const float* __restrict__ bk,
                                                   const float* __restrict__ query,
                                                   const float* __restrict__ Wq,
                                                   const float* __restrict__ bq,
                                                   const float* __restrict__ mask,
                                                   const float* __restrict__ qt,
                                                   const float* __restrict__ tt,
                                                   const float* __restrict__ stride_in,
                                                   const float* __restrict__ Wr,
                                                   const float* __restrict__ br,
                                                   float* __restrict__ kpT,
                                                   float* __restrict__ qp,
                                                   unsigned int* __restrict__ embitsT) {
    __shared__ float smem[5248 + 64];   // 128 mask rows (128*41) + strd
    const int bid = blockIdx.x;
    const int tid = threadIdx.x;

    if (bid < 1024) {
        // ---- kproj: rows bid*2, bid*2+1 -> kpT float layout b*32768 + (j>>2)*1024 + s*4 + (j&3)
        float* k0 = smem;
        float* k1 = smem + 48;
        const int half = tid >> 7;
        const int j = tid & 127;
        const int row = bid * 2 + half;
        if (j < DIM) (half ? k1 : k0)[j] = key[row * DIM + j];
        __syncthreads();
        const float* kr = half ? k1 : k0;
        float acc = bk[j];
#pragma unroll
        for (int i = 0; i < DIM; ++i) acc = fmaf(kr[i], Wk[i * ET + j], acc);
        const int b = row >> 8, s = row & 255;
        kpT[b * 32768 + (j >> 2) * 1024 + s * 4 + (j & 3)] = acc;
    } else if (bid < 1280) {
        // ---- qproj
        float* qlds = smem;             // [2][128]
        const int base = (bid - 1024) * 2;
        qlds[tid] = query[base * ET + tid];
        __syncthreads();
        const int half = tid >> 7;
        const int j = tid & 127;
        const float* qr = qlds + half * 128;
        float a0 = 0.f, a1 = 0.f, a2 = 0.f, a3 = 0.f;
#pragma unroll 8
        for (int i = 0; i < ET; i += 4) {
            a0 = fmaf(qr[i + 0], Wq[(i + 0) * ET + j], a0);
            a1 = fmaf(qr[i + 1], Wq[(i + 1) * ET + j], a1);
            a2 = fmaf(qr[i + 2], Wq[(i + 2) * ET + j], a2);
            a3 = fmaf(qr[i + 3], Wq[(i + 3) * ET + j], a3);
        }
        qp[(base + half) * ET + j] = bq[j] + ((a0 + a1) + (a2 + a3));
    } else {
        // ---- embitsT per (b,g): bit(s,d) = window & mask, d-major words:
        // embitsT[bg*328 + d*8 + (s>>5)], bit (s&31)
        float* mlds = smem;
        float* strd = smem + 5248;
        const int bg = bid - 1280;
        const int b = bg >> 6, g = bg & 63;
        if (tid < DIM) {
            float a = br[tid];
            for (int i = 0; i < DIM; ++i) a = fmaf(stride_in[i], Wr[i * DIM + tid], a);
            strd[tid] = 1.0f / (1.0f + expf(-a));
        }
        __syncthreads();
        const float qtg = qt[g];
        for (int rr = 0; rr < 2; ++rr) {
            for (int idx = tid; idx < 5248; idx += 256)
                mlds[idx] = mask[(size_t)b * S * DIM + rr * 5248 + idx];
            __syncthreads();
            if (tid < 128) {
                const int s = rr * 128 + tid;
                const float t = tt[b * S + s];
                const int wv = tid >> 6;
                const int w = rr * 2 + wv;
                unsigned int* op = embitsT + (size_t)bg * (DIM * 8) + w * 2;
#pragma unroll
                for (int d = 0; d < DIM; ++d) {
                    const float sd = strd[d];
                    const int ok = (t >= qtg - sd) & (t <= qtg + sd) & (mlds[tid * DIM + d] != 0.0f);
                    const unsigned long long bal = __ballot(ok);
                    if ((tid & 63) == 0) {
                        op[d * 8 + 0] = (unsigned int)bal;
                        op[d * 8 + 1] = (unsigned int)(bal >> 32);
                    }
                }
            }
            __syncthreads();
        }
    }
}

// ---------------- K2 "attn+outproj": per (bg, head-quad), 1024 blocks x 256 thr ----------------
// r8's proven attn structure; outproj fused as per-quad partial + atomicAdd (2 adds/output).
__global__ __launch_bounds__(256) void attn_kernel(const float* __restrict__ kpT,
                                                   const float* __restrict__ qp,
                                                   const unsigned int* __restrict__ embitsT,
                                                   const float* __restrict__ value,
                                                   const float* __restrict__ Wo,
                                                   const float* __restrict__ bo,
                                                   float* __restrict__ out) {
    __shared__ float elds[4 * EROW];    // e values per local head (padded rows)
    __shared__ float qlds[64];          // q fragment for these 4 heads
    __shared__ float Mb[4];
    __shared__ float xq[4 * DIM];       // this quad's x slice (164)
    __shared__ float po[2][128];

    const int bid = blockIdx.x;
    const int bg = bid >> 1;
    const int hq = bid & 1;             // head quad
    const int b = bg >> 6;
    const int tid = threadIdx.x;

    if (tid < 64) qlds[tid] = qp[(size_t)bg * ET + hq * 64 + tid];
    __syncthreads();

    // scores: thread = s, 4 local heads in registers
    float sc4[4];
    {
        const int s = tid;
        const float4* kb = reinterpret_cast<const float4*>(kpT) + (size_t)b * 8192 + s;
#pragma unroll
        for (int hl = 0; hl < 4; ++hl) {
            const int h = hq * 4 + hl;
            float a = 0.f;
#pragma unroll
            for (int e4 = 0; e4 < 4; ++e4) {
                const float4 kv = kb[(h * 4 + e4) * 256];
                a = fmaf(qlds[hl * EK + e4 * 4 + 0], kv.x, a);
                a = fmaf(qlds[hl * EK + e4 * 4 + 1], kv.y, a);
                a = fmaf(qlds[hl * EK + e4 * 4 + 2], kv.z, a);
                a = fmaf(qlds[hl * EK + e4 * 4 + 3], kv.w, a);
            }
            sc4[hl] = a * 0.25f;        // 1/sqrt(EK)
            elds[hl * EROW + s] = sc4[hl];
        }
    }
    __syncthreads();

    // per-head max: threads 0..127, hl = tid>>5, j = tid&31
    if (tid < 128) {
        const int hl = tid >> 5, j = tid & 31;
        float m = elds[hl * EROW + j];
#pragma unroll
        for (int k = 1; k < 8; ++k) m = fmaxf(m, elds[hl * EROW + j + 32 * k]);
#pragma unroll
        for (int off = 16; off; off >>= 1) m = fmaxf(m, __shfl_xor(m, off, 32));
        if (j == 0) Mb[hl] = m;
    }
    __syncthreads();

    // exp (from registers)
    {
        const int s = tid;
#pragma unroll
        for (int hl = 0; hl < 4; ++hl) elds[hl * EROW + s] = __expf(sc4[hl] - Mb[hl]);
    }
    __syncthreads();

    // weighted phase: wave = local head, lane = d; reduction-free
    {
        const int w = tid >> 6;         // local head
        const int d = tid & 63;
        if (d < DIM) {
            const uint4* bp = reinterpret_cast<const uint4*>(embitsT + (size_t)bg * (DIM * 8) + d * 8);
            const uint4 b0 = bp[0], b1 = bp[1];
            const unsigned int bw[8] = {b0.x, b0.y, b0.z, b0.w, b1.x, b1.y, b1.z, b1.w};
            const float* er = &elds[w * EROW];
            const float* vb = value + (size_t)b * S * DIM + d;
            float Ssum = 0.f, acc = 0.f;
#pragma unroll
            for (int k = 0; k < 8; ++k) {
                const unsigned int wv = bw[k];
#pragma unroll 8
                for (int i = 0; i < 32; ++i) {
                    const int s = k * 32 + i;
                    const float e = er[s];
                    const float v = vb[(size_t)s * DIM];
                    const float wgt = ((wv >> i) & 1u) ? e : 0.f;
                    Ssum += wgt;
                    acc = fmaf(wgt, v, acc);
                }
            }
            float r;
            if (Ssum != 0.f) {
                r = acc / Ssum;
            } else {
                // all-masked column: uniform softmax -> column mean (never taken in practice)
                float vs = 0.f;
                for (int s2 = 0; s2 < S; ++s2) vs += vb[(size_t)s2 * DIM];
                r = vs * (1.0f / S);
            }
            xq[w * DIM + d] = r;
        }
    }
    __syncthreads();

    // fused outproj partial: this quad covers Wo rows [hq*164, hq*164+164)
    {
        const int n = tid & 127, c = tid >> 7;   // 2 chunks of 82 rows
        if (n < NH) {
            const int i0 = c * 82;
            float a0 = 0.f, a1 = 0.f;
#pragma unroll 2
            for (int i = i0; i < i0 + 82; i += 2) {
                a0 = fmaf(xq[i],     Wo[(size_t)(hq * 164 + i) * NH + n],     a0);
                a1 = fmaf(xq[i + 1], Wo[(size_t)(hq * 164 + i + 1) * NH + n], a1);
            }
            po[c][n] = a0 + a1;
        }
    }
    __syncthreads();
    if (tid < NH) {
        float val = po[0][tid] + po[1][tid];
        if (hq == 0) val += bo[tid];             // bias added exactly once per output
        atomicAdd(&out[(size_t)bg * NH + tid], val);
    }
}

extern "C" void kernel_launch(void* const* d_in, const int* in_sizes, int n_in,
                              void* d_out, int out_size, void* d_ws, size_t ws_size,
                              hipStream_t stream) {
    const float* query     = (const float*)d_in[0];
    const float* key       = (const float*)d_in[1];
    const float* value     = (const float*)d_in[2];
    const float* mask      = (const float*)d_in[3];
    const float* qt        = (const float*)d_in[4];
    const float* tt        = (const float*)d_in[5];
    const float* stride_in = (const float*)d_in[6];
    const float* Wq        = (const float*)d_in[7];
    const float* bq        = (const float*)d_in[8];
    const float* Wk        = (const float*)d_in[9];
    const float* bk        = (const float*)d_in[10];
    const float* Wo        = (const float*)d_in[11];
    const float* bo        = (const float*)d_in[12];
    const float* Wr        = (const float*)d_in[13];
    const float* br        = (const float*)d_in[14];
    float* out = (float*)d_out;

    float* kpT = (float*)d_ws;                                         // 262144 f32
    float* qp = kpT + (size_t)B * H * 4 * S * 4;                       // 65536 f32
    unsigned int* embitsT = (unsigned int*)(qp + (size_t)B * G * ET);  // B*G*DIM*8 u32

    // out accumulates via atomicAdd -> zero it every call (graph-capturable async memset)
    hipMemsetAsync(out, 0, (size_t)out_size * sizeof(float), stream);

    prep_kernel<<<1792, 256, 0, stream>>>(key, Wk, bk, query, Wq, bq, mask, qt, tt,
                                          stride_in, Wr, br, kpT, qp, embitsT);
    attn_kernel<<<B * G * 2, 256, 0, stream>>>(kpT, qp, embitsT, value, Wo, bo, out);
}